// Round 3
// baseline (806.632 us; speedup 1.0000x reference)
//
#include <hip/hip_runtime.h>
#include <float.h>
#include <math.h>

// Problem constants (fixed by setup_inputs)
constexpr int Bn = 131072;  // points
constexpr int Dn = 256;     // feature dim
constexpr int Kn = 1024;    // clusters
constexpr int Ln = 526;     // label dim
constexpr float EPSF = 1e-8f;

constexpr int CHUNK = 128;                    // members per fused-kernel block
constexpr int MAXCHUNKS = Bn / CHUNK + Kn;    // 2048: sum ceil(n_k/C) <= B/C + K

// ---- assign kernel tiling (split-f16 MFMA GEMM, 8-phase schedule) ----
constexpr int BM  = 256;        // points per block
constexpr int BN  = 256;        // centroids per n-tile
constexpr int KC  = 32;         // logical K per chunk (f16 MFMA 16x16x32)
constexpr int NT  = Kn / BN;    // 4 n-tiles
constexpr int KCH = Dn / KC;    // 8 k-chunks
constexpr int NCH = NT * KCH;   // 32 chunks total

typedef _Float16 f16x8 __attribute__((ext_vector_type(8)));
typedef float    f32x4 __attribute__((ext_vector_type(4)));

__device__ __forceinline__ void dma16(const void* g, void* l) {
    __builtin_amdgcn_global_load_lds(
        (const __attribute__((address_space(1))) unsigned int*)g,
        (__attribute__((address_space(3))) unsigned int*)l, 16, 0, 0);
}

// ---------------- prep: c2[k], rln[k], pack centroids, zero accum buffers.
// cpk layout: [(k*8 + kchunk)*64 + j] j<32: hi, j>=32: lo  (128 B per (k,chunk))
__global__ __launch_bounds__(256) void prep_kernel(
    const float* __restrict__ centroids, const float* __restrict__ rlabels,
    float* __restrict__ c2, float* __restrict__ rln, _Float16* __restrict__ cpk,
    int* __restrict__ counts, float* __restrict__ o_disp,
    float* __restrict__ o_displab)
{
    const int k = blockIdx.x;
    const int t = threadIdx.x;
    float v = centroids[k * Dn + t];            // Dn == blockDim
    // pack split-f16
    {
        const int c = t >> 5, j = t & 31;
        const _Float16 h = (_Float16)v;
        const _Float16 l = (_Float16)(v - (float)h);
        cpk[((size_t)k * KCH + c) * 64 + j]      = h;
        cpk[((size_t)k * KCH + c) * 64 + 32 + j] = l;
    }
    float s1 = v * v;
    float s2 = 0.f;
    for (int i = t; i < Ln; i += 256) {
        float u = rlabels[(size_t)k * Ln + i];
        s2 += u * u;
    }
    for (int off = 32; off > 0; off >>= 1) {
        s1 += __shfl_down(s1, off, 64);
        s2 += __shfl_down(s2, off, 64);
    }
    __shared__ float red[8];
    const int wv = t >> 6;
    if ((t & 63) == 0) { red[wv * 2] = s1; red[wv * 2 + 1] = s2; }
    __syncthreads();
    if (t == 0) {
        c2[k]  = red[0] + red[2] + red[4] + red[6];
        rln[k] = sqrtf(red[1] + red[3] + red[5] + red[7]);
        counts[k] = 0;
        o_disp[k] = 0.f;
        o_displab[k] = 0.f;
    }
}

// ---------------- assignment: split-f16 MFMA GEMM, 256x256 tile, 8 waves,
// 4-phase-per-chunk schedule with counted vmcnt (never drains in loop).
// dot = Ah*Bh + Ah*Bl + Al*Bh (fp32-equivalent); t = c2 - 2*dot; argmin.
__global__ __launch_bounds__(512, 2) void assign_kernel(
    const float* __restrict__ points, const _Float16* __restrict__ cpk,
    const float* __restrict__ c2,
    float* __restrict__ o_assign, int* __restrict__ ws_assign,
    float* __restrict__ ws_tmin, int* __restrict__ counts)
{
    // LDS: [mat A=0/B=1][buf][row 256][64 f16 = hi32|lo32], 128 KiB.
    // 16-B slot q of a row holds logical slot q ^ (row&7) (XOR swizzle).
    __shared__ __align__(16) _Float16 lds[2][2][256][64];

    const int tid  = threadIdx.x;
    const int lane = tid & 63;
    const int wid  = tid >> 6;
    const int wrow = wid >> 1;          // 0..3: which 64-point row band
    const int wcol = wid & 1;           // 0..1: which 128-centroid col band
    const int ln15 = lane & 15;
    const int g    = lane >> 4;         // k-slot group (8 f16)
    const int bm0  = blockIdx.x * BM;

    // A staging mapping: thread -> (row, k-half)
    const int arow  = tid >> 1;         // 0..255
    const int ahalf = tid & 1;
    const int r7a   = arow & 7;

    // B DMA mapping
    const int rowl = lane >> 3;         // row within 8-row piece
    const int q8   = lane & 7;          // linear 16B slot within row

    f32x4 acc[4][8];
#pragma unroll
    for (int i = 0; i < 4; ++i)
#pragma unroll
        for (int j = 0; j < 8; ++j)
#pragma unroll
            for (int r = 0; r < 4; ++r) acc[i][j][r] = 0.f;

    float mint[16];
    unsigned int minkp[8];              // 2 x u16 packed
#pragma unroll
    for (int s = 0; s < 16; ++s) mint[s] = FLT_MAX;
#pragma unroll
    for (int s = 0; s < 8; ++s) minkp[s] = 0u;

    float4 pa[4];
    auto loadA = [&](int t) {
        const int kc = t & 7;
        const float* ap = points + (size_t)(bm0 + arow) * Dn + kc * KC + ahalf * 16;
        pa[0] = *(const float4*)(ap);
        pa[1] = *(const float4*)(ap + 4);
        pa[2] = *(const float4*)(ap + 8);
        pa[3] = *(const float4*)(ap + 12);
    };
    auto dmaB = [&](int t, int dbuf) {
        const int nt = t >> 3, kc = t & 7;
#pragma unroll
        for (int jj = 0; jj < 4; ++jj) {
            const int p  = wid * 4 + jj;            // piece 0..31, 8 rows each
            const int br = p * 8 + rowl;            // B row 0..255
            const int srcslot = q8 ^ (br & 7);      // pre-swizzled source
            const _Float16* gp = cpk
                + ((size_t)(nt * BN + br) * KCH + kc) * 64 + srcslot * 8;
            dma16(gp, &lds[1][dbuf][p * 8][0]);     // wave-uniform LDS base
        }
    };
    auto writeA = [&](int dbuf) {
        _Float16* Ar = &lds[0][dbuf][arow][0];
        const float vs[16] = {pa[0].x, pa[0].y, pa[0].z, pa[0].w,
                              pa[1].x, pa[1].y, pa[1].z, pa[1].w,
                              pa[2].x, pa[2].y, pa[2].z, pa[2].w,
                              pa[3].x, pa[3].y, pa[3].z, pa[3].w};
        f16x8 h0, h1, l0, l1;
#pragma unroll
        for (int u = 0; u < 8; ++u) {
            h0[u] = (_Float16)vs[u];     l0[u] = (_Float16)(vs[u]     - (float)h0[u]);
            h1[u] = (_Float16)vs[8 + u]; l1[u] = (_Float16)(vs[8 + u] - (float)h1[u]);
        }
        const int s0 = ahalf * 2;
        *(f16x8*)&Ar[((s0    ) ^ r7a) * 8] = h0;
        *(f16x8*)&Ar[((s0 + 1) ^ r7a) * 8] = h1;
        *(f16x8*)&Ar[((s0 + 4) ^ r7a) * 8] = l0;
        *(f16x8*)&Ar[((s0 + 5) ^ r7a) * 8] = l1;
    };

    f16x8 ah_[2], al_[2], bh_[4], bl_[4];
    auto rdA = [&](int buf, int mih) {
#pragma unroll
        for (int i = 0; i < 2; ++i) {
            const int r  = wrow * 64 + (mih * 2 + i) * 16 + ln15;
            const int r7 = r & 7;
            const _Float16* Ar = &lds[0][buf][r][0];
            ah_[i] = *(const f16x8*)&Ar[((g    ) ^ r7) * 8];
            al_[i] = *(const f16x8*)&Ar[((g + 4) ^ r7) * 8];
        }
    };
    auto rdB = [&](int buf, int njh) {
#pragma unroll
        for (int j = 0; j < 4; ++j) {
            const int r  = wcol * 128 + (njh * 4 + j) * 16 + ln15;
            const int r7 = r & 7;
            const _Float16* Br = &lds[1][buf][r][0];
            bh_[j] = *(const f16x8*)&Br[((g    ) ^ r7) * 8];
            bl_[j] = *(const f16x8*)&Br[((g + 4) ^ r7) * 8];
        }
    };
    auto mfmaQ = [&](int mih, int njh) {
#pragma unroll
        for (int i = 0; i < 2; ++i)
#pragma unroll
            for (int j = 0; j < 4; ++j) {
                f32x4& a = acc[mih * 2 + i][njh * 4 + j];
                a = __builtin_amdgcn_mfma_f32_16x16x32_f16(al_[i], bh_[j], a, 0, 0, 0);
                a = __builtin_amdgcn_mfma_f32_16x16x32_f16(ah_[i], bl_[j], a, 0, 0, 0);
                a = __builtin_amdgcn_mfma_f32_16x16x32_f16(ah_[i], bh_[j], a, 0, 0, 0);
            }
    };
    auto fold = [&](int nt) {
        const int nb = nt * BN + wcol * 128 + ln15;
#pragma unroll
        for (int nj = 0; nj < 8; ++nj) {
            const int n = nb + nj * 16;
            const float c2n = c2[n];
#pragma unroll
            for (int mi = 0; mi < 4; ++mi)
#pragma unroll
                for (int r = 0; r < 4; ++r) {
                    const float tv = fmaf(-2.f, acc[mi][nj][r], c2n);
                    const int s = mi * 4 + r;
                    const int idx = s >> 1;
                    const unsigned cur = (s & 1) ? (minkp[idx] >> 16)
                                                 : (minkp[idx] & 0xffffu);
                    if (tv < mint[s] || (tv == mint[s] && (unsigned)n < cur)) {
                        mint[s] = tv;
                        minkp[idx] = (s & 1)
                            ? ((minkp[idx] & 0x0000ffffu) | ((unsigned)n << 16))
                            : ((minkp[idx] & 0xffff0000u) | (unsigned)n);
                    }
                    acc[mi][nj][r] = 0.f;
                }
        }
    };

    // ---- prologue: stage chunk 0, prime pipeline (a(1) left in flight)
    loadA(0);
    dmaB(0, 0);
    asm volatile("s_waitcnt vmcnt(4)" ::: "memory");   // a(0) done
    writeA(0);
    loadA(1);
    asm volatile("s_waitcnt vmcnt(4)" ::: "memory");   // d(0) done
    asm volatile("s_waitcnt lgkmcnt(0)" ::: "memory");
    __builtin_amdgcn_s_barrier();

    // ---- main loop: 32 chunks x 4 phases
    for (int t = 0; t < NCH; ++t) {
        const int buf = t & 1, nxt = buf ^ 1;
        const bool last = (t == NCH - 1);

        // Phase 1: B nj0-3 + A mi0-1
        rdB(buf, 0); rdA(buf, 0);
        __builtin_amdgcn_s_barrier();
        __builtin_amdgcn_s_setprio(1); mfmaQ(0, 0); __builtin_amdgcn_s_setprio(0);
        __builtin_amdgcn_s_barrier();

        // Phase 2: A mi2-3; issue B-DMA(t+1)
        rdA(buf, 1);
        if (!last) dmaB(t + 1, nxt);
        __builtin_amdgcn_s_barrier();
        __builtin_amdgcn_s_setprio(1); mfmaQ(1, 0); __builtin_amdgcn_s_setprio(0);
        __builtin_amdgcn_s_barrier();

        // Phase 3: B nj4-7 + A mi0-1 (re); a(t+1) done -> write A(t+1)
        rdB(buf, 1); rdA(buf, 0);
        if (!last) {
            asm volatile("s_waitcnt vmcnt(4)" ::: "memory");
            writeA(nxt);
        }
        __builtin_amdgcn_s_barrier();
        __builtin_amdgcn_s_setprio(1); mfmaQ(0, 1); __builtin_amdgcn_s_setprio(0);
        asm volatile("s_waitcnt lgkmcnt(0)" ::: "memory");
        __builtin_amdgcn_s_barrier();

        // Phase 4: A mi2-3 (re); issue a(t+2); ensure d(t+1) landed
        rdA(buf, 1);
        if (t < NCH - 2) {
            loadA(t + 2);
            asm volatile("s_waitcnt vmcnt(4)" ::: "memory");  // d(t+1) done
        } else if (t == NCH - 2) {
            asm volatile("s_waitcnt vmcnt(0)" ::: "memory");  // drain d(t+1)
        }
        __builtin_amdgcn_s_setprio(1); mfmaQ(1, 1); __builtin_amdgcn_s_setprio(0);
        if ((t & 7) == 7) fold(t >> 3);
        __builtin_amdgcn_s_barrier();
    }

    // ---- epilogue: cross-lane argmin over the 16 centroid cols
    float rt[16]; int rk[16];
#pragma unroll
    for (int s = 0; s < 16; ++s) {
        float tv = mint[s];
        int kv = (int)((s & 1) ? (minkp[s >> 1] >> 16) : (minkp[s >> 1] & 0xffffu));
#pragma unroll
        for (int off = 1; off < 16; off <<= 1) {
            const float to = __shfl_xor(tv, off, 64);
            const int   ko = __shfl_xor(kv, off, 64);
            if (to < tv || (to == tv && ko < kv)) { tv = to; kv = ko; }
        }
        rt[s] = tv; rk[s] = kv;
    }
    __syncthreads();   // all frag reads done; reuse LDS for reduction
    float* redt = (float*)&lds[0][0][0][0];          // [256][2]
    int*   redk = (int*)(redt + 512);                // [256][2]
    if (ln15 == 0) {
#pragma unroll
        for (int s = 0; s < 16; ++s) {
            const int pr = wrow * 64 + (s >> 2) * 16 + g * 4 + (s & 3);
            redt[pr * 2 + wcol] = rt[s];
            redk[pr * 2 + wcol] = rk[s];
        }
    }
    __syncthreads();
    if (tid < BM) {
        float bt = redt[tid * 2];
        int   bk = redk[tid * 2];
        const float t1 = redt[tid * 2 + 1];
        const int   k1 = redk[tid * 2 + 1];
        if (t1 < bt || (t1 == bt && k1 < bk)) { bt = t1; bk = k1; }
        o_assign[bm0 + tid]  = (float)bk;
        ws_assign[bm0 + tid] = bk;
        ws_tmin[bm0 + tid]   = bt;
        atomicAdd(&counts[bk], 1);     // fused histogram
    }
}

// ---------------- exclusive scans over Kn=1024: shfl-based (4 barriers)
__global__ __launch_bounds__(1024) void scan_kernel(
    const int* __restrict__ counts, int* __restrict__ offsets,
    int* __restrict__ cursor, float* __restrict__ o_nn,
    int* __restrict__ chunk_off)
{
    __shared__ int wsum[16];
    __shared__ int wbase[16];
    const int t = threadIdx.x;
    const int lane = t & 63;
    const int w = t >> 6;

    const int c = counts[t];
    o_nn[t] = (float)c;

    // scan 1: counts
    int v = c;
#pragma unroll
    for (int off = 1; off < 64; off <<= 1) {
        const int u = __shfl_up(v, off, 64);
        if (lane >= off) v += u;
    }
    if (lane == 63) wsum[w] = v;
    __syncthreads();
    if (w == 0 && lane < 16) {
        int s = wsum[lane];
#pragma unroll
        for (int off = 1; off < 16; off <<= 1) {
            const int u = __shfl_up(s, off, 64);
            if (lane >= off) s += u;
        }
        wbase[lane] = s;   // inclusive
    }
    __syncthreads();
    const int incl = ((w == 0) ? 0 : wbase[w - 1]) + v;
    offsets[t] = incl - c;
    cursor[t]  = incl - c;
    __syncthreads();

    // scan 2: chunk counts
    const int cc = (c + CHUNK - 1) / CHUNK;
    int v2 = cc;
#pragma unroll
    for (int off = 1; off < 64; off <<= 1) {
        const int u = __shfl_up(v2, off, 64);
        if (lane >= off) v2 += u;
    }
    if (lane == 63) wsum[w] = v2;
    __syncthreads();
    if (w == 0 && lane < 16) {
        int s = wsum[lane];
#pragma unroll
        for (int off = 1; off < 16; off <<= 1) {
            const int u = __shfl_up(s, off, 64);
            if (lane >= off) s += u;
        }
        wbase[lane] = s;
    }
    __syncthreads();
    const int incl2 = ((w == 0) ? 0 : wbase[w - 1]) + v2;
    chunk_off[t] = incl2 - cc;
    if (t == Kn - 1) chunk_off[Kn] = incl2;
}

// ---------------- scatter point ids into cluster buckets
__global__ __launch_bounds__(256) void scatter_kernel(
    const int* __restrict__ assigni, int* __restrict__ cursor,
    int* __restrict__ bucket)
{
    const int p = blockIdx.x * 256 + threadIdx.x;
    const int a = assigni[p];
    const int idx = atomicAdd(&cursor[a], 1);
    bucket[idx] = p;
}

// ---------------- fused gather: per-chunk member-parallel, wave-per-member.
// Depth-2 member prefetch (gather is HBM-latency-bound); LDS-atomic column sums.
__global__ __launch_bounds__(256) void fused_cluster_kernel(
    const float* __restrict__ points, const float* __restrict__ labels,
    const float* __restrict__ rlabels,
    const int* __restrict__ bucket, const int* __restrict__ offsets,
    const int* __restrict__ counts, const int* __restrict__ chunk_off,
    const float* __restrict__ tmin, const float* __restrict__ rln,
    float* __restrict__ o_dist, float* __restrict__ o_disp,
    float* __restrict__ o_dlab, float* __restrict__ o_displab,
    float* __restrict__ o_nsum, float* __restrict__ o_nlab)
{
    const int b = blockIdx.x;
    if (b >= chunk_off[Kn]) return;           // uniform early-exit

    // binary search: largest k with chunk_off[k] <= b
    int lo = 0, hi = Kn;
    while (hi - lo > 1) {
        const int mid = (lo + hi) >> 1;
        if (chunk_off[mid] <= b) lo = mid; else hi = mid;
    }
    const int k   = lo;
    const int j   = b - chunk_off[k];
    const int nk  = counts[k];
    const int beg = offsets[k] + j * CHUNK;
    const int nm  = min(nk - j * CHUNK, CHUNK);
    const bool single = (nk <= CHUNK);

    const int tid  = threadIdx.x;
    const int lane = tid & 63;
    const int w    = tid >> 6;

    __shared__ int   sidx[CHUNK];
    __shared__ __align__(16) float srl[528];   // cluster's rlabel row
    __shared__ float sacc[784];                // 256 point cols + 526 label cols
    __shared__ float sdisp[4], sdlab[4];

    for (int i = tid; i < nm; i += 256) sidx[i] = bucket[beg + i];
    for (int i = tid; i < Ln; i += 256) srl[i] = rlabels[(size_t)k * Ln + i];
    for (int i = tid; i < 784; i += 256) sacc[i] = 0.f;
    __syncthreads();

    // loop-invariant rlabel fragments for this lane (float2 layout)
    const float2 rl0 = *(const float2*)&srl[2 * lane];
    const float2 rl1 = *(const float2*)&srl[2 * (64 + lane)];
    const float2 rl2 = *(const float2*)&srl[2 * (128 + lane)];
    const float2 rl3 = *(const float2*)&srl[2 * (192 + lane)];
    float2 rlT = make_float2(0.f, 0.f);
    if (lane < 7) rlT = *(const float2*)&srl[2 * (256 + lane)];
    const float rlnk = rln[k];

    float4 accP  = make_float4(0.f, 0.f, 0.f, 0.f);
    float2 accL0 = make_float2(0.f, 0.f), accL1 = accL0,
           accL2 = accL0, accL3 = accL0, accLT = accL0;
    float dispacc = 0.f, displabacc = 0.f;

    auto loadM = [&](int i, float4& pv, float2& a, float2& bb, float2& cc,
                     float2& dd, float2& ee, int& pid, float& tm) {
        pid = sidx[i];
        pv = ((const float4*)(points + (size_t)pid * Dn))[lane];
        const float2* l2p = (const float2*)(labels + (size_t)pid * Ln);
        a  = l2p[lane];
        bb = l2p[64 + lane];
        cc = l2p[128 + lane];
        dd = l2p[192 + lane];
        ee = (lane < 7) ? l2p[256 + lane] : make_float2(0.f, 0.f);
        tm = (lane == 0) ? tmin[pid] : 0.f;
    };

    // depth-2 register pipeline: wave w handles members w, w+4, ...
    float4 pv0 = make_float4(0,0,0,0), pv1 = pv0, pvX = pv0;
    float2 z2 = make_float2(0.f, 0.f);
    float2 a0 = z2, b0_ = z2, c0 = z2, d0 = z2, e0 = z2;
    float2 a1 = z2, b1_ = z2, c1 = z2, d1 = z2, e1 = z2;
    float2 aX = z2, bX_ = z2, cX = z2, dX = z2, eX = z2;
    int p0 = 0, p1 = 0, pX = 0; float t0 = 0.f, t1 = 0.f, tX = 0.f;

    int i = w;
    if (i < nm)     loadM(i,     pv0, a0, b0_, c0, d0, e0, p0, t0);
    if (i + 4 < nm) loadM(i + 4, pv1, a1, b1_, c1, d1, e1, p1, t1);
    while (i < nm) {
        if (i + 8 < nm) loadM(i + 8, pvX, aX, bX_, cX, dX, eX, pX, tX);

        // accumulate column sums
        accP.x += pv0.x; accP.y += pv0.y; accP.z += pv0.z; accP.w += pv0.w;
        accL0.x += a0.x;  accL0.y += a0.y;
        accL1.x += b0_.x; accL1.y += b0_.y;
        accL2.x += c0.x;  accL2.y += c0.y;
        accL3.x += d0.x;  accL3.y += d0.y;
        accLT.x += e0.x;  accLT.y += e0.y;

        // per-member reductions
        float x2m = pv0.x * pv0.x + pv0.y * pv0.y + pv0.z * pv0.z + pv0.w * pv0.w;
        float l2m = a0.x * a0.x + a0.y * a0.y + b0_.x * b0_.x + b0_.y * b0_.y
                  + c0.x * c0.x + c0.y * c0.y + d0.x * d0.x + d0.y * d0.y
                  + e0.x * e0.x + e0.y * e0.y;
        float dtm = a0.x * rl0.x + a0.y * rl0.y + b0_.x * rl1.x + b0_.y * rl1.y
                  + c0.x * rl2.x + c0.y * rl2.y + d0.x * rl3.x + d0.y * rl3.y
                  + e0.x * rlT.x + e0.y * rlT.y;
#pragma unroll
        for (int off = 1; off < 64; off <<= 1) {
            x2m += __shfl_xor(x2m, off, 64);
            l2m += __shfl_xor(l2m, off, 64);
            dtm += __shfl_xor(dtm, off, 64);
        }
        if (lane == 0) {
            const float dist = x2m + t0;                 // x2 - 2 p.c + c2
            o_dist[p0] = dist;
            const float dl = 1.0f - dtm / (sqrtf(l2m) * rlnk + EPSF);
            o_dlab[p0] = dl;
            dispacc += dist;
            displabacc += dl;
        }

        pv0 = pv1; a0 = a1; b0_ = b1_; c0 = c1; d0 = d1; e0 = e1; p0 = p1; t0 = t1;
        pv1 = pvX; a1 = aX; b1_ = bX_; c1 = cX; d1 = dX; e1 = eX; p1 = pX; t1 = tX;
        i += 4;
    }

    if (lane == 0) { sdisp[w] = dispacc; sdlab[w] = displabacc; }

    // cross-wave column reduction via LDS float atomics (no wave serialization)
    {
        atomicAdd(&sacc[4 * lane + 0], accP.x);
        atomicAdd(&sacc[4 * lane + 1], accP.y);
        atomicAdd(&sacc[4 * lane + 2], accP.z);
        atomicAdd(&sacc[4 * lane + 3], accP.w);
        float* sl = sacc + 256;
        atomicAdd(&sl[2 * lane],           accL0.x); atomicAdd(&sl[2 * lane + 1],       accL0.y);
        atomicAdd(&sl[128 + 2 * lane],     accL1.x); atomicAdd(&sl[128 + 2 * lane + 1], accL1.y);
        atomicAdd(&sl[256 + 2 * lane],     accL2.x); atomicAdd(&sl[256 + 2 * lane + 1], accL2.y);
        atomicAdd(&sl[384 + 2 * lane],     accL3.x); atomicAdd(&sl[384 + 2 * lane + 1], accL3.y);
        if (lane < 7) {
            atomicAdd(&sl[512 + 2 * lane],     accLT.x);
            atomicAdd(&sl[512 + 2 * lane + 1], accLT.y);
        }
    }
    __syncthreads();

    // write block partials (direct store if this cluster has a single chunk)
    float* np = o_nsum + (size_t)k * Dn;
    float* nl = o_nlab + (size_t)k * Ln;
    const float vP  = sacc[tid];
    const float vL0 = sacc[256 + tid];
    const float vL1 = sacc[512 + tid];
    if (single) {
        np[tid]       = vP;
        nl[tid]       = vL0;
        nl[tid + 256] = vL1;
        if (tid < 14) nl[tid + 512] = sacc[768 + tid];
    } else {
        atomicAdd(&np[tid], vP);
        atomicAdd(&nl[tid], vL0);
        atomicAdd(&nl[tid + 256], vL1);
        if (tid < 14) atomicAdd(&nl[tid + 512], sacc[768 + tid]);
    }
    if (tid == 0) {
        const float dsum  = sdisp[0] + sdisp[1] + sdisp[2] + sdisp[3];
        const float dlsum = sdlab[0] + sdlab[1] + sdlab[2] + sdlab[3];
        if (single) { o_disp[k] = dsum; o_displab[k] = dlsum; }
        else { atomicAdd(&o_disp[k], dsum); atomicAdd(&o_displab[k], dlsum); }
    }
}

extern "C" void kernel_launch(void* const* d_in, const int* in_sizes, int n_in,
                              void* d_out, int out_size, void* d_ws, size_t ws_size,
                              hipStream_t stream)
{
    const float* points    = (const float*)d_in[0];   // (B, D)
    const float* labels    = (const float*)d_in[1];   // (B, L)
    const float* centroids = (const float*)d_in[2];   // (K, D)
    const float* rlabels   = (const float*)d_in[3];   // (K, L)

    float* out = (float*)d_out;
    float* o_assign  = out;                       // B
    float* o_dist    = out + Bn;                  // B
    float* o_disp    = out + 2 * Bn;              // K
    float* o_dlab    = o_disp + Kn;               // B
    float* o_displab = o_dlab + Bn;               // K
    float* o_nsum    = o_displab + Kn;            // K*D
    float* o_nn      = o_nsum + Kn * Dn;          // K
    float* o_nlab    = o_nn + Kn;                 // K*L

    float* ws        = (float*)d_ws;
    float* c2        = ws;                          // Kn
    float* rln       = ws + Kn;                     // Kn
    float* tmin      = ws + 2 * Kn;                 // Bn
    int*   assigni   = (int*)(ws + 2 * Kn + Bn);    // Bn
    int*   counts    = assigni + Bn;                // Kn
    int*   offsets   = counts + Kn;                 // Kn
    int*   cursor    = offsets + Kn;                // Kn
    int*   bucket    = cursor + Kn;                 // Bn
    int*   chunk_off = bucket + Bn;                 // Kn+1
    _Float16* cpk    = (_Float16*)(ws + 400000);    // Kn*512 f16 = 1 MB, 16B-aligned

    // zero atomic-accumulated big regions (counts/disp zeroed in prep_kernel)
    hipMemsetAsync(o_nsum, 0, (size_t)Kn * Dn * sizeof(float), stream);
    hipMemsetAsync(o_nlab, 0, (size_t)Kn * Ln * sizeof(float), stream);

    prep_kernel<<<Kn, 256, 0, stream>>>(centroids, rlabels, c2, rln, cpk,
                                        counts, o_disp, o_displab);
    assign_kernel<<<Bn / BM, 512, 0, stream>>>(points, cpk, c2,
                                               o_assign, assigni, tmin, counts);
    scan_kernel<<<1, Kn, 0, stream>>>(counts, offsets, cursor, o_nn, chunk_off);
    scatter_kernel<<<Bn / 256, 256, 0, stream>>>(assigni, cursor, bucket);
    fused_cluster_kernel<<<MAXCHUNKS, 256, 0, stream>>>(
        points, labels, rlabels, bucket, offsets, counts, chunk_off,
        tmin, rln, o_dist, o_disp, o_dlab, o_displab, o_nsum, o_nlab);
}